// Round 9
// baseline (80.015 us; speedup 1.0000x reference)
//
#include <hip/hip_runtime.h>
#include <stdint.h>

#define BB 16
#define TT 4096
#define DDIM 512
#define KK 128
#define TCB 128            // t-rows per chunk
#define NCB (TT / TCB)     // 32 chunks
#define PI_F 3.14159265358979323846f

typedef unsigned short u16;
typedef __attribute__((ext_vector_type(8))) short short8;
typedef __attribute__((ext_vector_type(4))) float f32x4;

__device__ __forceinline__ uint32_t cvt_bf16_rn(float f) {
  uint32_t u = __float_as_uint(f);
  return (u + 0x7FFFu + ((u >> 16) & 1u)) >> 16;
}
__device__ __forceinline__ uint32_t pack2(float a, float b) {
  return cvt_bf16_rn(a) | (cvt_bf16_rn(b) << 16);
}
__device__ __forceinline__ uint4 pack8(const float4 f0, const float4 f1) {
  uint4 r;
  r.x = pack2(f0.x, f0.y);
  r.y = pack2(f0.z, f0.w);
  r.z = pack2(f1.x, f1.y);
  r.w = pack2(f1.z, f1.w);
  return r;
}
__device__ __forceinline__ void gload_lds16(const void* g, void* l) {
  __builtin_amdgcn_global_load_lds(
      (const __attribute__((address_space(1))) void*)g,
      (__attribute__((address_space(3))) void*)l, 16, 0, 0);
}
#define AT_LD(p) __hip_atomic_load((p), __ATOMIC_RELAXED, __HIP_MEMORY_SCOPE_AGENT)
#define AT_ST(p, v) __hip_atomic_store((p), (v), __ATOMIC_RELAXED, __HIP_MEMORY_SCOPE_AGENT)

// ---------------- kernel 0: fused prep (wpack | ct | params) ----------------
__global__ __launch_bounds__(256) void k_prep(
    const float* __restrict__ W, const float* __restrict__ u_sn,
    const float* __restrict__ s_real_raw, const float* __restrict__ s_imag,
    const float* __restrict__ bias, const float* __restrict__ b_log,
    const float* __restrict__ dt,
    float* __restrict__ params, u16* __restrict__ Wp, float* __restrict__ ct) {
  int gb = blockIdx.x;
  int tid = threadIdx.x;
  if (gb < 64) {
    int idx = gb * 256 + tid;
    int k = idx >> 7;
    int d = (idx & 127) * 4;
    float4 v = *(const float4*)&W[(size_t)k * DDIM + d];
    int tile = d >> 6, dl = d & 63;
    int slot = (dl >> 3) ^ (k & 7);
    int e = dl & 7;  // 0 or 4
    size_t base = (size_t)tile * 8192 + k * 64 + slot * 8 + e;
    uint2 p;
    p.x = pack2(v.x, v.y);
    p.y = pack2(v.z, v.w);
    *(uint2*)&Wp[base] = p;
  } else if (gb < 80) {
    __shared__ float sc[256];
    int b = gb - 64;
    const float* row = dt + (size_t)b * TT;
    float* orow = ct + (size_t)b * TT;
    float loc[16];
    float s = 0.f;
    int base = tid * 16;
    for (int i = 0; i < 16; ++i) { s += row[base + i]; loc[i] = s; }
    sc[tid] = s;
    __syncthreads();
    for (int off = 1; off < 256; off <<= 1) {
      float v = (tid >= off) ? sc[tid - off] : 0.f;
      __syncthreads();
      sc[tid] += v;
      __syncthreads();
    }
    float excl = sc[tid] - s;
    for (int i = 0; i < 16; ++i) orow[base + i] = excl + loc[i];
  } else {
    __shared__ float su[KK];
    __shared__ float sv[DDIM];
    __shared__ float red[4];
    __shared__ float s_sig;
    if (tid < KK) su[tid] = u_sn[tid];
    __syncthreads();
    for (int rep = 0; rep < 2; ++rep) {
      int d = tid + rep * 256;
      float acc = 0.f;
      for (int k = 0; k < KK; ++k) acc += W[k * DDIM + d] * su[k];
      sv[d] = acc;
    }
    __syncthreads();
    float nn = 0.f;
    for (int rep = 0; rep < 2; ++rep) { float v = sv[tid + rep * 256]; nn += v * v; }
    for (int off = 32; off > 0; off >>= 1) nn += __shfl_down(nn, off, 64);
    if ((tid & 63) == 0) red[tid >> 6] = nn;
    __syncthreads();
    float vn2 = red[0] + red[1] + red[2] + red[3];
    __syncthreads();
    float vinv = 1.f / (sqrtf(vn2) + 1e-6f);
    for (int rep = 0; rep < 2; ++rep) sv[tid + rep * 256] *= vinv;
    __syncthreads();
    float wv = 0.f;
    if (tid < KK) {
      const float* wrow = W + (size_t)tid * DDIM;
      for (int d = 0; d < DDIM; ++d) wv += wrow[d] * sv[d];
    }
    float q = wv * wv;
    for (int off = 32; off > 0; off >>= 1) q += __shfl_down(q, off, 64);
    if ((tid & 63) == 0) red[tid >> 6] = q;
    __syncthreads();
    if (tid == 0) {
      float wn2 = red[0] + red[1] + red[2] + red[3];
      s_sig = wn2 / (sqrtf(wn2) + 1e-6f);
    }
    __syncthreads();
    if (tid < KK) {
      float inv_sigma = 1.f / s_sig;
      float sr = s_real_raw[tid];
      float alpha = ((sr > 20.f) ? sr : log1pf(expf(sr))) + 1e-6f;
      float om = fminf(fmaxf(s_imag[tid], -PI_F), PI_F);
      float bg = expf(b_log[tid]);
      params[tid] = alpha;
      params[KK + tid] = om;
      params[2 * KK + tid] = bg * inv_sigma;
      params[3 * KK + tid] = bg * bias[tid];
    }
  }
}

// ---------------- kernel 1: counted-vmcnt pipelined GEMM + reduce + per-b sync + finalize ----------------
// T3/T4: raw s_barrier + counted s_waitcnt vmcnt(N); prefetches (W 1-iter deep
// via LDS dbuf, x 2-iter deep via regs) stay in flight ACROSS barriers.
__global__ __launch_bounds__(512, 4) void k_fused(
    const float* __restrict__ x, const u16* __restrict__ Wp,
    const float* __restrict__ dt, const float* __restrict__ ct,
    const float* __restrict__ params, float* __restrict__ out,
    float* __restrict__ csum_re, float* __restrict__ csum_im,
    int* __restrict__ cnt) {
  __shared__ __align__(16) u16 smem[32768];   // 64 KB
  // u16 offsets: Xbuf0 @0, Xbuf1 @8192, Wbuf0 @16384, Wbuf1 @24576

  const int chunk = blockIdx.x, b = blockIdx.y;
  const int tid = threadIdx.x;
  const int wv = tid >> 6, l = tid & 63;
  const int lm = l & 15, lg = l >> 4;
  const int kw = wv & 1, tw = wv >> 1;
  const int t0 = chunk * TCB;

  const int xr = tid >> 2, xq = (tid & 3) * 16;
  const size_t xbase = ((size_t)b * TT + t0 + xr) * DDIM + xq;
  const int xs0 = ((xq >> 3) ^ (xr & 7)) * 8;
  const int xs1 = (((xq >> 3) + 1) ^ (xr & 7)) * 8;

  f32x4 acc[2][4];
#pragma unroll
  for (int m = 0; m < 2; ++m)
#pragma unroll
    for (int n = 0; n < 4; ++n) acc[m][n] = (f32x4)(0.0f);

  float4 xa[4], xb[4];
  const char* wsrc = (const char*)Wp + (size_t)tid * 16;
  char* wdst = (char*)smem + 32768 + tid * 16;   // Wbuf0 dest for this thread

  // ---- prologue: W0->Wbuf0, x0->xa | W1->Wbuf1, x1->xb | wait W0,x0 | pack x0
  {
    gload_lds16(wsrc, wdst);
    gload_lds16(wsrc + 8192, wdst + 8192);
    const float* xp = x + xbase;
    xa[0] = *(const float4*)(xp + 0);
    xa[1] = *(const float4*)(xp + 4);
    xa[2] = *(const float4*)(xp + 8);
    xa[3] = *(const float4*)(xp + 12);
    __builtin_amdgcn_sched_barrier(0);
    gload_lds16(wsrc + 16384, wdst + 16384);
    gload_lds16(wsrc + 24576, wdst + 24576);
    const float* xp1 = x + xbase + 64;
    xb[0] = *(const float4*)(xp1 + 0);
    xb[1] = *(const float4*)(xp1 + 4);
    xb[2] = *(const float4*)(xp1 + 8);
    xb[3] = *(const float4*)(xp1 + 12);
    __builtin_amdgcn_sched_barrier(0);
    asm volatile("s_waitcnt vmcnt(6)" ::: "memory");   // W0, x0 done
    __builtin_amdgcn_sched_barrier(0);
    *(uint4*)&smem[xr * 64 + xs0] = pack8(xa[0], xa[1]);
    *(uint4*)&smem[xr * 64 + xs1] = pack8(xa[2], xa[3]);
    asm volatile("s_waitcnt lgkmcnt(0)" ::: "memory");
    __builtin_amdgcn_sched_barrier(0);
  }

  // ---- main loop: vmcnt schedule [4,6,6,6,6,6,2,0]
#pragma unroll
  for (int j = 0; j < 8; ++j) {
    const int p = j & 1;
    // A: issue W(j+1) -> Wbuf[(j+1)&1]  (j in [1,6]; W1 already issued)
    if (j >= 1 && j <= 6) {
      const char* wsg = (const char*)Wp + (size_t)(j + 1) * 16384 + tid * 16;
      char* wd = (char*)smem + 32768 + ((j + 1) & 1) * 16384 + tid * 16;
      gload_lds16(wsg, wd);
      gload_lds16(wsg + 8192, wd + 8192);
    }
    // B: issue x(j+2) -> reg set (j&1)  (j in [0,5])
    if (j <= 5) {
      const float* xp = x + xbase + (size_t)(j + 2) * 64;
      if (p == 0) {
        xa[0] = *(const float4*)(xp + 0);
        xa[1] = *(const float4*)(xp + 4);
        xa[2] = *(const float4*)(xp + 8);
        xa[3] = *(const float4*)(xp + 12);
      } else {
        xb[0] = *(const float4*)(xp + 0);
        xb[1] = *(const float4*)(xp + 4);
        xb[2] = *(const float4*)(xp + 8);
        xb[3] = *(const float4*)(xp + 12);
      }
    }
    __builtin_amdgcn_sched_barrier(0);
    // C: counted wait — completes W(j) and x(j+1), leaves newer prefetches in flight
    if (j == 0)      asm volatile("s_waitcnt vmcnt(4)" ::: "memory");
    else if (j == 6) asm volatile("s_waitcnt vmcnt(2)" ::: "memory");
    else if (j == 7) asm volatile("s_waitcnt vmcnt(0)" ::: "memory");
    else             asm volatile("s_waitcnt vmcnt(6)" ::: "memory");
    __builtin_amdgcn_sched_barrier(0);
    // D: publish W(j) + x(j) buffers block-wide
    __builtin_amdgcn_s_barrier();
    __builtin_amdgcn_sched_barrier(0);
    // E: MFMA on buffers p
    {
      const u16* xbuf = smem + p * 8192;
      const u16* wbuf = smem + 16384 + p * 8192;
#pragma unroll
      for (int ks = 0; ks < 2; ++ks) {
        short8 fa[2], fb[4];
#pragma unroll
        for (int m = 0; m < 2; ++m) {
          int row = tw * 32 + m * 16 + lm;
          int sw = ((ks * 4 + lg) ^ (row & 7)) * 8;
          fa[m] = *(const short8*)&xbuf[row * 64 + sw];
        }
#pragma unroll
        for (int n = 0; n < 4; ++n) {
          int row = kw * 64 + n * 16 + lm;
          int sw = ((ks * 4 + lg) ^ (row & 7)) * 8;
          fb[n] = *(const short8*)&wbuf[row * 64 + sw];
        }
#pragma unroll
        for (int m = 0; m < 2; ++m)
#pragma unroll
          for (int n = 0; n < 4; ++n)
            acc[m][n] = __builtin_amdgcn_mfma_f32_16x16x32_bf16(fa[m], fb[n], acc[m][n], 0, 0, 0);
      }
    }
    __builtin_amdgcn_sched_barrier(0);
    // F: pack x(j+1) (arrived per C) into Xbuf[p^1]  (j in [0,6])
    if (j <= 6) {
      u16* xw = smem + (p ^ 1) * 8192;
      if (((j + 1) & 1) == 0) {
        *(uint4*)&xw[xr * 64 + xs0] = pack8(xa[0], xa[1]);
        *(uint4*)&xw[xr * 64 + xs1] = pack8(xa[2], xa[3]);
      } else {
        *(uint4*)&xw[xr * 64 + xs0] = pack8(xb[0], xb[1]);
        *(uint4*)&xw[xr * 64 + xs1] = pack8(xb[2], xb[3]);
      }
    }
    __builtin_amdgcn_sched_barrier(0);
    // G: seal LDS ops, then barrier (no vmcnt drain!)
    asm volatile("s_waitcnt lgkmcnt(0)" ::: "memory");
    __builtin_amdgcn_s_barrier();
    __builtin_amdgcn_sched_barrier(0);
  }

  // ---- persistent LDS (survives the sync phase)
  float* totr = (float*)smem;          // [4][128]
  float* toti = (float*)smem + 512;    // [4][128]
  float* pre_ = (float*)smem + 1024;   // [256]

  float dtv[2][4], ctv[2][4];
#pragma unroll
  for (int m = 0; m < 2; ++m)
#pragma unroll
    for (int r = 0; r < 4; ++r) {
      int t = t0 + tw * 32 + m * 16 + lg * 4 + r;
      dtv[m][r] = dt[(size_t)b * TT + t];
      ctv[m][r] = ct[(size_t)b * TT + t];
    }

  // ---- pre-sync: per-n transform + REDUCE to wave totals
#pragma unroll
  for (int n = 0; n < 4; ++n) {
    int k = kw * 64 + n * 16 + lm;
    float pal = params[k], pom = params[KK + k];
    float pc1 = params[2 * KK + k], pc2 = params[3 * KK + k];
    float sr = 0.f, si2 = 0.f;
#pragma unroll
    for (int m = 0; m < 2; ++m)
#pragma unroll
      for (int r = 0; r < 4; ++r) {
        float g = acc[m][n][r];
        float a = pal * dtv[m][r];
        float omr = a * (1.f - a * (0.5f - a * (1.f / 6.f)));  // 1 - exp(-a)
        float itv = omr * (pc1 * g + pc2);
        float e = __expf(pal * ctv[m][r]);
        float sn, cs;
        __sincosf(pom * ctv[m][r], &sn, &cs);
        sr += itv * e * cs;
        si2 -= itv * e * sn;
      }
    sr += __shfl_xor(sr, 16, 64);
    sr += __shfl_xor(sr, 32, 64);
    si2 += __shfl_xor(si2, 16, 64);
    si2 += __shfl_xor(si2, 32, 64);
    if (lg == 0) { totr[tw * KK + k] = sr; toti[tw * KK + k] = si2; }
  }
  __syncthreads();
  // ---- publish chunk totals (relaxed agent atomics)
  if (tid < 256) {
    int v = tid & 127;
    float* src = (tid < 128) ? totr : toti;
    float* dst = (tid < 128) ? csum_re : csum_im;
    float tot = (src[v] + src[KK + v]) + (src[2 * KK + v] + src[3 * KK + v]);
    AT_ST(&dst[((size_t)b * NCB + chunk) * KK + v], tot);
  }
  __syncthreads();
  if (tid == 0) {
    __threadfence();
    __hip_atomic_fetch_add(&cnt[b * 64], 1, __ATOMIC_RELAXED, __HIP_MEMORY_SCOPE_AGENT);
  }

  // ---- designated prefixer: chunk-0 block turns totals into exclusive prefixes
  if (chunk == 0) {
    if (tid == 0)
      while (AT_LD(&cnt[b * 64]) < NCB) __builtin_amdgcn_s_sleep(2);
    __syncthreads();
    if (tid < 256) {
      int v = tid & 127;
      float* srcp = (tid < 128) ? csum_re : csum_im;
      size_t base = (size_t)b * NCB * KK + v;
      float vals[NCB];
#pragma unroll
      for (int c = 0; c < NCB; ++c) vals[c] = AT_LD(&srcp[base + (size_t)c * KK]);
      float run = 0.f;
#pragma unroll
      for (int c = 0; c < NCB; ++c) { float t = vals[c]; AT_ST(&srcp[base + (size_t)c * KK], run); run += t; }
    }
    __syncthreads();
    if (tid == 0) {
      __threadfence();
      AT_ST(&cnt[b * 64 + 32], 1);
    }
  }
  // ---- all blocks: wait for prefixes, read own row
  if (tid == 0)
    while (AT_LD(&cnt[b * 64 + 32]) == 0) __builtin_amdgcn_s_sleep(2);
  __syncthreads();
  if (tid < 256) {
    int v = tid & 127;
    float* srcp = (tid < 128) ? csum_re : csum_im;
    pre_[tid] = AT_LD(&srcp[((size_t)b * NCB + chunk) * KK + v]);
  }
  __syncthreads();

  // ---- post-sync: recompute transform from acc, scan, rotate, store
#pragma unroll
  for (int n = 0; n < 4; ++n) {
    int k = kw * 64 + n * 16 + lm;
    float pal = params[k], pom = params[KK + k];
    float pc1 = params[2 * KK + k], pc2 = params[3 * KK + k];
    float cr = pre_[k], ci = pre_[KK + k];
    for (int t2 = 0; t2 < tw; ++t2) { cr += totr[t2 * KK + k]; ci += toti[t2 * KK + k]; }
#pragma unroll
    for (int m = 0; m < 2; ++m) {
      float vr[4], vi[4], e4[4], sn4[4], cs4[4];
#pragma unroll
      for (int r = 0; r < 4; ++r) {
        float g = acc[m][n][r];
        float a = pal * dtv[m][r];
        float omr = a * (1.f - a * (0.5f - a * (1.f / 6.f)));
        float itv = omr * (pc1 * g + pc2);
        float e = __expf(pal * ctv[m][r]);
        float sn, cs;
        __sincosf(pom * ctv[m][r], &sn, &cs);
        e4[r] = e; sn4[r] = sn; cs4[r] = cs;
        vr[r] = itv * e * cs;
        vi[r] = -(itv * e) * sn;
      }
      vr[1] += vr[0]; vr[2] += vr[1]; vr[3] += vr[2];
      vi[1] += vi[0]; vi[2] += vi[1]; vi[3] += vi[2];
      float ar = vr[3], ai = vi[3];
      float tr0 = ar, ti0 = ai;
      float ur = __shfl_up(ar, 16, 64);
      float ui = __shfl_up(ai, 16, 64);
      if (lg >= 1) { ar += ur; ai += ui; }
      ur = __shfl_up(ar, 32, 64);
      ui = __shfl_up(ai, 32, 64);
      if (lg >= 2) { ar += ur; ai += ui; }
      float exr = ar - tr0 + cr;
      float exi = ai - ti0 + ci;
      cr += __shfl(ar, 48 + lm, 64);
      ci += __shfl(ai, 48 + lm, 64);
#pragma unroll
      for (int r = 0; r < 4; ++r) {
        float Sre = vr[r] + exr;
        float Sim = vi[r] + exi;
        float dec = __builtin_amdgcn_rcpf(e4[r]);   // e^{-alpha*ct} = 1/e
        float sn = sn4[r], cs = cs4[r];
        float Rw = dec * (cs * Sre - sn * Sim);
        float Iw = dec * (cs * Sim + sn * Sre);
        size_t rowb = ((size_t)b * TT + t0 + tw * 32 + m * 16 + lg * 4 + r) * (2 * KK);
        out[rowb + k] = Rw - Iw;        // C
        out[rowb + KK + k] = Rw + Iw;   // S
      }
    }
  }
}

extern "C" void kernel_launch(void* const* d_in, const int* in_sizes, int n_in,
                              void* d_out, int out_size, void* d_ws, size_t ws_size,
                              hipStream_t stream) {
  const float* x    = (const float*)d_in[0];
  const float* dt   = (const float*)d_in[1];
  const float* srr  = (const float*)d_in[2];
  const float* si   = (const float*)d_in[3];
  const float* W    = (const float*)d_in[4];
  const float* bias = (const float*)d_in[5];
  const float* blog = (const float*)d_in[6];
  const float* usn  = (const float*)d_in[7];
  float* out = (float*)d_out;
  float* ws = (float*)d_ws;

  float* params  = ws;                          // 512 f
  float* ct      = ws + 4 * KK;                 // 65536 f
  float* csum_re = ct + (size_t)BB * TT;        // 65536 f
  float* csum_im = csum_re + (size_t)BB * NCB * KK;
  u16*   Wp      = (u16*)(csum_im + (size_t)BB * NCB * KK);  // 65536 u16 (128 KB)
  int*   cnt     = (int*)(Wp + 65536);          // 16*64 ints (counter + flag2, padded)

  hipMemsetAsync(cnt, 0, 16 * 64 * sizeof(int), stream);
  k_prep<<<81, 256, 0, stream>>>(W, usn, srr, si, bias, blog, dt, params, Wp, ct);
  k_fused<<<dim3(NCB, BB), 512, 0, stream>>>(x, Wp, dt, ct, params, out,
                                             csum_re, csum_im, cnt);
}

// Round 10
// 69.582 us; speedup vs baseline: 1.1499x; 1.1499x over previous
//
#include <hip/hip_runtime.h>
#include <stdint.h>

#define BB 16
#define TT 4096
#define DDIM 512
#define KK 128
#define TCB 128            // t-rows per chunk
#define NCB (TT / TCB)     // 32 chunks
#define PI_F 3.14159265358979323846f

typedef unsigned short u16;
typedef __attribute__((ext_vector_type(8))) short short8;
typedef __attribute__((ext_vector_type(4))) float f32x4;

__device__ __forceinline__ uint32_t cvt_bf16_rn(float f) {
  uint32_t u = __float_as_uint(f);
  return (u + 0x7FFFu + ((u >> 16) & 1u)) >> 16;
}
__device__ __forceinline__ uint32_t pack2(float a, float b) {
  return cvt_bf16_rn(a) | (cvt_bf16_rn(b) << 16);
}
__device__ __forceinline__ uint4 pack8(const float4 f0, const float4 f1) {
  uint4 r;
  r.x = pack2(f0.x, f0.y);
  r.y = pack2(f0.z, f0.w);
  r.z = pack2(f1.x, f1.y);
  r.w = pack2(f1.z, f1.w);
  return r;
}
__device__ __forceinline__ float bf16_to_f32(u16 v) {
  return __uint_as_float(((uint32_t)v) << 16);
}
__device__ __forceinline__ void gload_lds16(const void* g, void* l) {
  __builtin_amdgcn_global_load_lds(
      (const __attribute__((address_space(1))) void*)g,
      (__attribute__((address_space(3))) void*)l, 16, 0, 0);
}

// ---------------- kernel 0: fused prep (wpack | ct | params) ----------------
__global__ __launch_bounds__(256) void k_prep(
    const float* __restrict__ W, const float* __restrict__ u_sn,
    const float* __restrict__ s_real_raw, const float* __restrict__ s_imag,
    const float* __restrict__ bias, const float* __restrict__ b_log,
    const float* __restrict__ dt,
    float* __restrict__ params, u16* __restrict__ Wp, float* __restrict__ ct) {
  int gb = blockIdx.x;
  int tid = threadIdx.x;
  if (gb < 64) {
    int idx = gb * 256 + tid;
    int k = idx >> 7;
    int d = (idx & 127) * 4;
    float4 v = *(const float4*)&W[(size_t)k * DDIM + d];
    int tile = d >> 6, dl = d & 63;
    int slot = (dl >> 3) ^ (k & 7);
    int e = dl & 7;  // 0 or 4
    size_t base = (size_t)tile * 8192 + k * 64 + slot * 8 + e;
    uint2 p;
    p.x = pack2(v.x, v.y);
    p.y = pack2(v.z, v.w);
    *(uint2*)&Wp[base] = p;
  } else if (gb < 80) {
    __shared__ float sc[256];
    int b = gb - 64;
    const float* row = dt + (size_t)b * TT;
    float* orow = ct + (size_t)b * TT;
    float loc[16];
    float s = 0.f;
    int base = tid * 16;
    for (int i = 0; i < 16; ++i) { s += row[base + i]; loc[i] = s; }
    sc[tid] = s;
    __syncthreads();
    for (int off = 1; off < 256; off <<= 1) {
      float v = (tid >= off) ? sc[tid - off] : 0.f;
      __syncthreads();
      sc[tid] += v;
      __syncthreads();
    }
    float excl = sc[tid] - s;
    for (int i = 0; i < 16; ++i) orow[base + i] = excl + loc[i];
  } else {
    __shared__ float su[KK];
    __shared__ float sv[DDIM];
    __shared__ float red[4];
    __shared__ float s_sig;
    if (tid < KK) su[tid] = u_sn[tid];
    __syncthreads();
    for (int rep = 0; rep < 2; ++rep) {
      int d = tid + rep * 256;
      float acc = 0.f;
      for (int k = 0; k < KK; ++k) acc += W[k * DDIM + d] * su[k];
      sv[d] = acc;
    }
    __syncthreads();
    float nn = 0.f;
    for (int rep = 0; rep < 2; ++rep) { float v = sv[tid + rep * 256]; nn += v * v; }
    for (int off = 32; off > 0; off >>= 1) nn += __shfl_down(nn, off, 64);
    if ((tid & 63) == 0) red[tid >> 6] = nn;
    __syncthreads();
    float vn2 = red[0] + red[1] + red[2] + red[3];
    __syncthreads();
    float vinv = 1.f / (sqrtf(vn2) + 1e-6f);
    for (int rep = 0; rep < 2; ++rep) sv[tid + rep * 256] *= vinv;
    __syncthreads();
    float wv = 0.f;
    if (tid < KK) {
      const float* wrow = W + (size_t)tid * DDIM;
      for (int d = 0; d < DDIM; ++d) wv += wrow[d] * sv[d];
    }
    float q = wv * wv;
    for (int off = 32; off > 0; off >>= 1) q += __shfl_down(q, off, 64);
    if ((tid & 63) == 0) red[tid >> 6] = q;
    __syncthreads();
    if (tid == 0) {
      float wn2 = red[0] + red[1] + red[2] + red[3];
      s_sig = wn2 / (sqrtf(wn2) + 1e-6f);
    }
    __syncthreads();
    if (tid < KK) {
      float inv_sigma = 1.f / s_sig;
      float sr = s_real_raw[tid];
      float alpha = ((sr > 20.f) ? sr : log1pf(expf(sr))) + 1e-6f;
      float om = fminf(fmaxf(s_imag[tid], -PI_F), PI_F);
      float bg = expf(b_log[tid]);
      params[tid] = alpha;
      params[KK + tid] = om;
      params[2 * KK + tid] = bg * inv_sigma;
      params[3 * KK + tid] = bg * bias[tid];
    }
  }
}

// ---------------- kernel A: pipelined GEMM -> itv (bf16) + chunk totals ----------------
// No atomics, no grid sync, no post-phase. D[t][k] MFMA; per-iter dbuf pipeline.
__global__ __launch_bounds__(512, 4) void k_gemm(
    const float* __restrict__ x, const u16* __restrict__ Wp,
    const float* __restrict__ dt, const float* __restrict__ ct,
    const float* __restrict__ params, u16* __restrict__ itvb,
    float* __restrict__ csum_re, float* __restrict__ csum_im) {
  __shared__ __align__(16) u16 smem[32768];   // 64 KB
  // u16 offsets: Xbuf0 @0, Xbuf1 @8192, Wbuf0 @16384, Wbuf1 @24576

  const int chunk = blockIdx.x, b = blockIdx.y;
  const int tid = threadIdx.x;
  const int wv = tid >> 6, l = tid & 63;
  const int lm = l & 15, lg = l >> 4;
  const int kw = wv & 1, tw = wv >> 1;
  const int t0 = chunk * TCB;

  const int xr = tid >> 2, xq = (tid & 3) * 16;
  const size_t xbase = ((size_t)b * TT + t0 + xr) * DDIM + xq;
  const int xs0 = ((xq >> 3) ^ (xr & 7)) * 8;
  const int xs1 = (((xq >> 3) + 1) ^ (xr & 7)) * 8;

  f32x4 acc[2][4];
#pragma unroll
  for (int m = 0; m < 2; ++m)
#pragma unroll
    for (int n = 0; n < 4; ++n) acc[m][n] = (f32x4)(0.0f);

  // ---- prologue: stage tile 0 into buffer 0
  {
    const char* wsg = (const char*)Wp + (size_t)tid * 16;
    char* wd = (char*)smem + 32768 + tid * 16;
    gload_lds16(wsg, wd);
    gload_lds16(wsg + 8192, wd + 8192);
    const float* xp = x + xbase;
    float4 f0 = *(const float4*)(xp + 0);
    float4 f1 = *(const float4*)(xp + 4);
    float4 f2 = *(const float4*)(xp + 8);
    float4 f3 = *(const float4*)(xp + 12);
    *(uint4*)&smem[xr * 64 + xs0] = pack8(f0, f1);
    *(uint4*)&smem[xr * 64 + xs1] = pack8(f2, f3);
  }
  __syncthreads();

  int cur = 0;
  for (int it = 0; it < 8; ++it) {
    float4 f0, f1, f2, f3;
    // phase 1: issue next-tile loads (x -> regs, W -> LDS via DMA)
    if (it < 7) {
      const float* xp = x + xbase + (it + 1) * 64;
      f0 = *(const float4*)(xp + 0);
      f1 = *(const float4*)(xp + 4);
      f2 = *(const float4*)(xp + 8);
      f3 = *(const float4*)(xp + 12);
      const char* wsg = (const char*)Wp + (size_t)(it + 1) * 16384 + tid * 16;
      char* wd = (char*)smem + 32768 + (cur ^ 1) * 16384 + tid * 16;
      gload_lds16(wsg, wd);
      gload_lds16(wsg + 8192, wd + 8192);
    }
    __builtin_amdgcn_sched_barrier(0);
    // phase 2: MFMA on current buffers
    {
      const u16* xb = smem + cur * 8192;
      const u16* wb = smem + 16384 + cur * 8192;
#pragma unroll
      for (int ks = 0; ks < 2; ++ks) {
        short8 fa[2], fb[4];
#pragma unroll
        for (int m = 0; m < 2; ++m) {
          int row = tw * 32 + m * 16 + lm;
          int sw = ((ks * 4 + lg) ^ (row & 7)) * 8;
          fa[m] = *(const short8*)&xb[row * 64 + sw];
        }
#pragma unroll
        for (int n = 0; n < 4; ++n) {
          int row = kw * 64 + n * 16 + lm;
          int sw = ((ks * 4 + lg) ^ (row & 7)) * 8;
          fb[n] = *(const short8*)&wb[row * 64 + sw];
        }
#pragma unroll
        for (int m = 0; m < 2; ++m)
#pragma unroll
          for (int n = 0; n < 4; ++n)
            acc[m][n] = __builtin_amdgcn_mfma_f32_16x16x32_bf16(fa[m], fb[n], acc[m][n], 0, 0, 0);
      }
    }
    __builtin_amdgcn_sched_barrier(0);
    // phase 3: convert prefetched x, write to next buffer
    if (it < 7) {
      u16* xb = smem + (cur ^ 1) * 8192;
      *(uint4*)&xb[xr * 64 + xs0] = pack8(f0, f1);
      *(uint4*)&xb[xr * 64 + xs1] = pack8(f2, f3);
    }
    __syncthreads();
    cur ^= 1;
  }

  // ---- epilogue: itv -> LDS (bf16) + rotated chunk-total reduce
  float* totr = (float*)smem;          // [4][128]  bytes 0..2048
  float* toti = (float*)smem + 512;    // bytes 2048..4096
  u16* litv = smem + 8192;             // [128 t][128 k] u16, bytes 16384..49152

  float dtv[2][4], ctv[2][4];
#pragma unroll
  for (int m = 0; m < 2; ++m)
#pragma unroll
    for (int r = 0; r < 4; ++r) {
      int t = t0 + tw * 32 + m * 16 + lg * 4 + r;
      dtv[m][r] = dt[(size_t)b * TT + t];
      ctv[m][r] = ct[(size_t)b * TT + t];
    }

#pragma unroll
  for (int n = 0; n < 4; ++n) {
    int k = kw * 64 + n * 16 + lm;
    float pal = params[k], pom = params[KK + k];
    float pc1 = params[2 * KK + k], pc2 = params[3 * KK + k];
    float sr = 0.f, si2 = 0.f;
#pragma unroll
    for (int m = 0; m < 2; ++m)
#pragma unroll
      for (int r = 0; r < 4; ++r) {
        float g = acc[m][n][r];
        float a = pal * dtv[m][r];
        float omr = a * (1.f - a * (0.5f - a * (1.f / 6.f)));  // 1 - exp(-a)
        float itv = omr * (pc1 * g + pc2);
        int tl = tw * 32 + m * 16 + lg * 4 + r;
        litv[tl * KK + k] = (u16)cvt_bf16_rn(itv);
        float e = __expf(pal * ctv[m][r]);
        float sn, cs;
        __sincosf(pom * ctv[m][r], &sn, &cs);
        sr += itv * e * cs;
        si2 -= itv * e * sn;
      }
    sr += __shfl_xor(sr, 16, 64);
    sr += __shfl_xor(sr, 32, 64);
    si2 += __shfl_xor(si2, 16, 64);
    si2 += __shfl_xor(si2, 32, 64);
    if (lg == 0) { totr[tw * KK + k] = sr; toti[tw * KK + k] = si2; }
  }
  __syncthreads();

  // chunk totals (plain stores; dispatch boundary syncs with kernel B)
  if (tid < 256) {
    int v = tid & 127;
    float* src = (tid < 128) ? totr : toti;
    float* dst = (tid < 128) ? csum_re : csum_im;
    dst[((size_t)b * NCB + chunk) * KK + v] =
        (src[v] + src[KK + v]) + (src[2 * KK + v] + src[3 * KK + v]);
  }
  // itv coalesced store: 16 threads x 16B per row, 32 rows per round, 4 rounds
  {
    int row = tid >> 4;          // 0..31
    int c8 = (tid & 15) * 8;     // u16 offset
#pragma unroll
    for (int rr = 0; rr < 4; ++rr) {
      int tr = rr * 32 + row;
      uint4 v = *(const uint4*)&litv[tr * KK + c8];
      *(uint4*)&itvb[((size_t)b * TT + t0 + tr) * KK + c8] = v;
    }
  }
}

// ---------------- kernel B: prefix + 2-pass scan + rotate + coalesced store ----------------
__global__ __launch_bounds__(512) void k_final(
    const u16* __restrict__ itvb, const float* __restrict__ ct,
    const float* __restrict__ params,
    const float* __restrict__ csum_re, const float* __restrict__ csum_im,
    float* __restrict__ out) {
  __shared__ float prer[KK], prei[KK];
  __shared__ float segr[4][KK], segi[4][KK];
  const int chunk = blockIdx.x, b = blockIdx.y;
  const int tid = threadIdx.x;
  const int k = tid & 127, tseg = tid >> 7;   // 4 segments x 32 t
  const int tbase = chunk * TCB + tseg * 32;

  // cross-chunk prefix (csum written by kernel A; dispatch boundary = visible)
  if (tid < 256) {
    int v = tid & 127;
    const float* srcp = (tid < 128) ? csum_re : csum_im;
    float* dstp = (tid < 128) ? prer : prei;
    size_t base = (size_t)b * NCB * KK + v;
    float a0 = 0.f, a1 = 0.f, a2 = 0.f, a3 = 0.f;
    int c = 0;
    for (; c + 4 <= chunk; c += 4) {
      a0 += srcp[base + (size_t)(c + 0) * KK];
      a1 += srcp[base + (size_t)(c + 1) * KK];
      a2 += srcp[base + (size_t)(c + 2) * KK];
      a3 += srcp[base + (size_t)(c + 3) * KK];
    }
    for (; c < chunk; ++c) a0 += srcp[base + (size_t)c * KK];
    dstp[v] = (a0 + a1) + (a2 + a3);
  }

  const float pal = params[k], pom = params[KK + k];
  // pass 1: segment totals
  float sr = 0.f, si = 0.f;
#pragma unroll 4
  for (int i = 0; i < 32; ++i) {
    int t = tbase + i;
    float itv = bf16_to_f32(itvb[((size_t)b * TT + t) * KK + k]);
    float ctv = ct[(size_t)b * TT + t];
    float e = __expf(pal * ctv);
    float sn, cs;
    __sincosf(pom * ctv, &sn, &cs);
    sr += itv * e * cs;
    si -= itv * e * sn;
  }
  segr[tseg][k] = sr;
  segi[tseg][k] = si;
  __syncthreads();
  float cr = prer[k], ci = prei[k];
  for (int s = 0; s < tseg; ++s) { cr += segr[s][k]; ci += segi[s][k]; }
  // pass 2: inclusive scan + rotate + store (coalesced 512B rows)
#pragma unroll 4
  for (int i = 0; i < 32; ++i) {
    int t = tbase + i;
    float itv = bf16_to_f32(itvb[((size_t)b * TT + t) * KK + k]);
    float ctv = ct[(size_t)b * TT + t];
    float e = __expf(pal * ctv);
    float sn, cs;
    __sincosf(pom * ctv, &sn, &cs);
    cr += itv * e * cs;
    ci -= itv * e * sn;
    float dec = __builtin_amdgcn_rcpf(e);   // e^{-alpha*ct}
    float Rw = dec * (cs * cr - sn * ci);
    float Iw = dec * (cs * ci + sn * cr);
    size_t rowb = ((size_t)b * TT + t) * (2 * KK);
    out[rowb + k] = Rw - Iw;        // C
    out[rowb + KK + k] = Rw + Iw;   // S
  }
}

extern "C" void kernel_launch(void* const* d_in, const int* in_sizes, int n_in,
                              void* d_out, int out_size, void* d_ws, size_t ws_size,
                              hipStream_t stream) {
  const float* x    = (const float*)d_in[0];
  const float* dt   = (const float*)d_in[1];
  const float* srr  = (const float*)d_in[2];
  const float* si   = (const float*)d_in[3];
  const float* W    = (const float*)d_in[4];
  const float* bias = (const float*)d_in[5];
  const float* blog = (const float*)d_in[6];
  const float* usn  = (const float*)d_in[7];
  float* out = (float*)d_out;
  float* ws = (float*)d_ws;

  float* params  = ws;                          // 512 f
  float* ct      = ws + 4 * KK;                 // 65536 f
  float* csum_re = ct + (size_t)BB * TT;        // 65536 f
  float* csum_im = csum_re + (size_t)BB * NCB * KK;  // 65536 f
  u16*   Wp      = (u16*)(csum_im + (size_t)BB * NCB * KK);  // 65536 u16
  u16*   itvb    = Wp + 65536;                  // B*T*K u16 = 16 MB

  k_prep<<<81, 256, 0, stream>>>(W, usn, srr, si, bias, blog, dt, params, Wp, ct);
  k_gemm<<<dim3(NCB, BB), 512, 0, stream>>>(x, Wp, dt, ct, params, itvb,
                                            csum_re, csum_im);
  k_final<<<dim3(NCB, BB), 512, 0, stream>>>(itvb, ct, params,
                                             csum_re, csum_im, out);
}